// Round 8
// baseline (234.390 us; speedup 1.0000x reference)
//
#include <hip/hip_runtime.h>

#define Hdim 512
#define Wdim 512
#define Cdim 256
#define CQ 64            // Cdim/4 float4 quads per line
#define OUTH 7
#define OUTW 7
#define TS 32            // tile edge
#define NT 16            // tiles per dim = 512/32
#define CG 64            // channels per K1 block
#define NROI_BINS (OUTH * OUTW)

typedef float f32x4 __attribute__((ext_vector_type(4)));

static constexpr size_t SLOC_ELEMS = (size_t)Hdim * Wdim * Cdim;   // ~268 MB
static constexpr size_t EL_ELEMS   = (size_t)Hdim * NT * Cdim;     // ~8.4 MB
static constexpr size_t F_ELEMS    = (size_t)NT * Wdim * Cdim;     // ~8.4 MB

// ---------------- K1: per-tile local 2D SAT (32x32 tiles) -------------------
__global__ void local_sat(const float* __restrict__ x, float* __restrict__ Sloc) {
    const int cg = blockIdx.x & 3;
    const int tJ = (blockIdx.x >> 2) & (NT - 1);
    const int tI = blockIdx.x >> 6;
    const int c  = cg * CG + threadIdx.x;

    const size_t base = ((size_t)(tI * TS) * Wdim + (size_t)(tJ * TS)) * Cdim + c;
    const float* xp = x + base;
    float* sp = Sloc + base;

    float P[TS];
    #pragma unroll
    for (int w = 0; w < TS; ++w) P[w] = 0.f;

    float va[TS], vb[TS];
    #pragma unroll
    for (int w = 0; w < TS; ++w) va[w] = xp[(size_t)w * Cdim];   // row 0

    #pragma unroll
    for (int h = 0; h < TS; ++h) {
        const float* cur = (h & 1) ? vb : va;
        float*       nxt = (h & 1) ? va : vb;
        if (h + 1 < TS) {
            #pragma unroll
            for (int w = 0; w < TS; ++w)
                nxt[w] = xp[((size_t)(h + 1) * Wdim + w) * Cdim];
        }
        float rowAcc = 0.f;
        #pragma unroll
        for (int w = 0; w < TS; ++w) {
            rowAcc += cur[w];
            P[w] += rowAcc;
            sp[((size_t)h * Wdim + w) * Cdim] = P[w];
        }
    }
}

// ---------------- K2a: E_left[h][J][c] = sum_{J'<J} Sloc[h][32J'+31][c] -----
__global__ void make_eleft(const float* __restrict__ Sloc, float* __restrict__ EL) {
    const int h = blockIdx.x;
    const int c = threadIdx.x;
    const float* sp = Sloc + (size_t)h * Wdim * Cdim + c;
    float* ep = EL + (size_t)h * NT * Cdim + c;

    double acc = 0.0;
    #pragma unroll
    for (int J = 0; J < NT; ++J) {
        const float t = sp[(size_t)(J * TS + TS - 1) * Cdim];
        ep[(size_t)J * Cdim] = (float)acc;
        acc += (double)t;
    }
}

// ---------------- K2b: F[I][w][c] = sum_{I'<I} (Sloc[32I'+31][w][c]
//                                               + EL[32I'+31][w>>5][c]) ------
__global__ void make_f(const float* __restrict__ Sloc, const float* __restrict__ EL,
                       float* __restrict__ F) {
    const int w = blockIdx.x;
    const int c = threadIdx.x;
    const int J = w >> 5;
    const float* sp = Sloc + (size_t)w * Cdim + c;
    const float* ep = EL + (size_t)J * Cdim + c;
    float* fp = F + (size_t)w * Cdim + c;

    double acc = 0.0;
    #pragma unroll
    for (int I = 0; I < NT; ++I) {
        const int hb = I * TS + TS - 1;
        const float a = sp[(size_t)hb * Wdim * Cdim];
        const float b = ep[(size_t)hb * NT * Cdim];
        fp[(size_t)I * Wdim * Cdim] = (float)acc;
        acc += (double)a + (double)b;
    }
}

// ---------------- shared bin-edge math (replicates reference exactly) ------
__device__ __forceinline__ void roi_bounds(const float4 r, int& hs, int& ws,
                                           int& rh, int& rw) {
    hs = (int)floorf((float)Hdim * r.x);
    ws = (int)floorf((float)Wdim * r.y);
    int he = (int)floorf((float)Hdim * r.z);
    int we = (int)floorf((float)Wdim * r.w);
    he = max(he, hs + 1);
    we = max(we, ws + 1);
    rh = he - hs;
    rw = we - ws;
}

// ---------------- K0: spatial counting-sort of ROI indices ------------------
// Single block. Bucket = 32x32 tile of ROI origin (16x16 = 256 buckets).
// perm is a bijection; within-bucket order is atomic-race-dependent but the
// gather's OUTPUT is independent of perm order (each ROI owns its out slice).
__global__ void sort_rois(const float4* __restrict__ rois, int* __restrict__ perm,
                          int N) {
    __shared__ int base[256];
    const int t = threadIdx.x;

    if (t < 256) base[t] = 0;
    __syncthreads();

    for (int n = t; n < N; n += blockDim.x) {
        const float4 r = rois[n];
        int hs, ws, rh, rw; roi_bounds(r, hs, ws, rh, rw);
        const int key = ((hs >> 5) << 4) | (ws >> 5);
        atomicAdd(&base[key], 1);
    }
    __syncthreads();
    if (t == 0) {                      // serial exclusive prefix over 256
        int a = 0;
        for (int k = 0; k < 256; ++k) { const int v = base[k]; base[k] = a; a += v; }
    }
    __syncthreads();
    for (int n = t; n < N; n += blockDim.x) {
        const float4 r = rois[n];
        int hs, ws, rh, rw; roi_bounds(r, hs, ws, rh, rw);
        const int key = ((hs >> 5) << 4) | (ws >> 5);
        const int pos = atomicAdd(&base[key], 1);
        perm[pos] = n;
    }
}

// ---------------- K3: gather, one wave per (sorted roi, out-row) ------------
__global__ __launch_bounds__(64, 4) void gather_kernel(
        const f32x4* __restrict__ Sloc, const f32x4* __restrict__ EL,
        const f32x4* __restrict__ F, const float4* __restrict__ rois,
        const int* __restrict__ perm, f32x4* __restrict__ out, int N) {
    const int b = blockIdx.x;
    const int n = perm[b / OUTH];
    const int i = b % OUTH;
    const int q = threadIdx.x;      // 0..63

    const float4 r = rois[n];       // y0,x0,y1,x1
    int hs, ws, rh, rw;
    roi_bounds(r, hs, ws, rh, rw);

    const int hb0 = hs + (i * rh) / OUTH;
    const int hb1 = hs + ((i + 1) * rh + OUTH - 1) / OUTH;   // ceil div
    const float dh = (float)(hb1 - hb0);

    const int  h1 = hb1 - 1;                 // hb1 >= 1 always
    const int  h0 = max(hb0 - 1, 0);
    const float mh0 = (hb0 > 0) ? 1.f : 0.f;
    const int  I1 = h1 >> 5, I0 = h0 >> 5;

    f32x4* op = out + ((size_t)(n * OUTH + i) * OUTW) * CQ + q;

    #pragma unroll
    for (int j = 0; j < OUTW; ++j) {
        const int wb0 = ws + (j * rw) / OUTW;
        const int wb1 = ws + ((j + 1) * rw + OUTW - 1) / OUTW;
        const int w1 = wb1 - 1;              // wb1 >= 1 always
        const int w0 = max(wb0 - 1, 0);
        const float mw0 = (wb0 > 0) ? 1.f : 0.f;
        const int J1 = w1 >> 5, J0 = w0 >> 5;

        // 4 Sloc loads — unconditional, cacheable (sorted order -> reuse)
        const f32x4 a11 = Sloc[((size_t)h1 * Wdim + w1) * CQ + q];
        const f32x4 a01 = Sloc[((size_t)h0 * Wdim + w1) * CQ + q];
        const f32x4 a10 = Sloc[((size_t)h1 * Wdim + w0) * CQ + q];
        const f32x4 a00 = Sloc[((size_t)h0 * Wdim + w0) * CQ + q];
        // F / EL (L2/L3-hot, 16.8 MB combined)
        const f32x4 f11 = F[((size_t)I1 * Wdim + w1) * CQ + q];
        const f32x4 f01 = F[((size_t)I0 * Wdim + w1) * CQ + q];
        const f32x4 f10 = F[((size_t)I1 * Wdim + w0) * CQ + q];
        const f32x4 f00 = F[((size_t)I0 * Wdim + w0) * CQ + q];
        const f32x4 e11 = EL[((size_t)h1 * NT + J1) * CQ + q];
        const f32x4 e01 = EL[((size_t)h0 * NT + J1) * CQ + q];
        const f32x4 e10 = EL[((size_t)h1 * NT + J0) * CQ + q];
        const f32x4 e00 = EL[((size_t)h0 * NT + J0) * CQ + q];

        const f32x4 s11 = a11 + f11 + e11;
        const f32x4 s01 = (a01 + f01 + e01) * mh0;
        const f32x4 s10 = (a10 + f10 + e10) * mw0;
        const f32x4 s00 = (a00 + f00 + e00) * (mh0 * mw0);

        const float inv = 1.0f / (dh * (float)(wb1 - wb0));
        const f32x4 o = (((s11 - s01) - s10) + s00) * inv;
        __builtin_nontemporal_store(o, &op[(size_t)j * CQ]);
    }
}

// ---------------- Fallback: direct per-bin summation (ws too small) --------
__global__ void direct_kernel(const float* __restrict__ x,
                              const float* __restrict__ rois,
                              float* __restrict__ out, int N) {
    const int bid = blockIdx.x;
    const int n = bid / NROI_BINS;
    const int rem = bid % NROI_BINS;
    const int i = rem / OUTW;
    const int j = rem % OUTW;
    const int c = threadIdx.x;
    if (n >= N) return;

    const float4 r = reinterpret_cast<const float4*>(rois)[n];
    int hs, ws, rh, rw;
    roi_bounds(r, hs, ws, rh, rw);

    const int hb0 = hs + (i * rh) / OUTH;
    const int hb1 = hs + ((i + 1) * rh + OUTH - 1) / OUTH;
    const int wb0 = ws + (j * rw) / OUTW;
    const int wb1 = ws + ((j + 1) * rw + OUTW - 1) / OUTW;

    double acc = 0.0;
    for (int h = hb0; h < hb1; ++h) {
        const float* xp = x + ((size_t)h * Wdim) * Cdim + c;
        for (int w = wb0; w < wb1; ++w)
            acc += (double)xp[(size_t)w * Cdim];
    }
    const float area = (float)((hb1 - hb0) * (wb1 - wb0));
    out[((size_t)bid) * Cdim + c] = (float)(acc / (double)area);
}

extern "C" void kernel_launch(void* const* d_in, const int* in_sizes, int n_in,
                              void* d_out, int out_size, void* d_ws, size_t ws_size,
                              hipStream_t stream) {
    const float* x    = (const float*)d_in[0];
    const float* rois = (const float*)d_in[1];
    float* out        = (float*)d_out;
    const int N       = in_sizes[1] / 4;   // 2000

    const size_t ws_need = (SLOC_ELEMS + EL_ELEMS + F_ELEMS) * sizeof(float)
                         + (size_t)N * sizeof(int);
    if (ws_size >= ws_need) {
        float* Sloc = (float*)d_ws;
        float* EL   = Sloc + SLOC_ELEMS;
        float* F    = EL + EL_ELEMS;
        int*   perm = (int*)(F + F_ELEMS);
        sort_rois<<<1, 1024, 0, stream>>>((const float4*)rois, perm, N);
        local_sat<<<NT * NT * 4, CG, 0, stream>>>(x, Sloc);
        make_eleft<<<Hdim, Cdim, 0, stream>>>(Sloc, EL);
        make_f<<<Wdim, Cdim, 0, stream>>>(Sloc, EL, F);
        gather_kernel<<<N * OUTH, 64, 0, stream>>>(
            (const f32x4*)Sloc, (const f32x4*)EL, (const f32x4*)F,
            (const float4*)rois, perm, (f32x4*)out, N);
    } else {
        direct_kernel<<<N * NROI_BINS, Cdim, 0, stream>>>(x, rois, out, N);
    }
}